// Round 9
// baseline (446.042 us; speedup 1.0000x reference)
//
#include <hip/hip_runtime.h>

#define CH 128
#define NPB 16    // nodes per block in k_edge

typedef _Float16 f16;
typedef _Float16 f16x8 __attribute__((ext_vector_type(8)));
typedef float f32x4 __attribute__((ext_vector_type(4)));

__device__ __forceinline__ f32x4 mfma16(f16x8 a, f16x8 b, f32x4 c) {
    return __builtin_amdgcn_mfma_f32_16x16x32_f16(a, b, c, 0, 0, 0);
}

// Barrier that waits LDS ops only — does NOT drain vmcnt, so global prefetches
// issued for future tiles stay in flight across the barrier (m97/hipBLASLt lesson).
__device__ __forceinline__ void bar_lds() {
    asm volatile("s_waitcnt lgkmcnt(0)\n\ts_barrier" ::: "memory");
}

// ---------------- fused front: hist + weight prep (3 layers) + x->f16 cvt ----------------
__global__ __launch_bounds__(256) void k_front(const int* __restrict__ edst, int* __restrict__ counts, int E,
                                               const float* __restrict__ W1a, const float* __restrict__ W2a,
                                               const float* __restrict__ W1b, const float* __restrict__ W2b,
                                               const float* __restrict__ W1c, const float* __restrict__ W2c,
                                               f16* __restrict__ WcT, f16* __restrict__ W2T,
                                               const float* __restrict__ x, f16* __restrict__ act,
                                               int total4, int gHist) {
    int bid = blockIdx.x;
    if (bid < gHist) {
        int e = bid * 256 + threadIdx.x;
        if (e < E) atomicAdd(&counts[edst[e]], 1);
    } else if (bid < gHist + 576) {
        int r = bid - gHist;
        int l = r / 192;
        const float* W1 = (l == 0) ? W1a : (l == 1) ? W1b : W1c;
        const float* W2 = (l == 0) ? W2a : (l == 1) ? W2b : W2c;
        f16* wct = WcT + l * 256 * CH;
        f16* w2t = W2T + l * CH * CH;
        int id = (r % 192) * 256 + threadIdx.x;   // 49152 per layer
        if (id < 32768) {
            int n = id >> 7, k = id & 127;
            float v;
            if (n < CH) v = W1[k * CH + n] - W1[(CH + k) * CH + n];
            else        v = W1[(CH + k) * CH + (n - CH)];
            wct[n * CH + k] = (f16)v;
        } else {
            int rr = id - 32768;
            int n = rr >> 7, k = rr & 127;
            w2t[n * CH + k] = (f16)W2[k * CH + n];
        }
    } else {
        int i = (bid - gHist - 576) * 256 + threadIdx.x;
        if (i < total4) {
            float4 v = ((const float4*)x)[i];
            f16 h0 = (f16)v.x, h1 = (f16)v.y, h2 = (f16)v.z, h3 = (f16)v.w;
            short4 s;
            s.x = *(short*)&h0; s.y = *(short*)&h1; s.z = *(short*)&h2; s.w = *(short*)&h3;
            ((short4*)act)[i] = s;
        }
    }
}

// ---------------- CSR scans + scatter ----------------
__global__ __launch_bounds__(256) void k_scan1(const int* __restrict__ counts, int* __restrict__ row_ptr,
                                               int* __restrict__ blockSums, int n) {
    __shared__ int s[256];
    int t = threadIdx.x;
    int i = blockIdx.x * 256 + t;
    s[t] = (i < n) ? counts[i] : 0;
    __syncthreads();
    for (int off = 1; off < 256; off <<= 1) {
        int x = (t >= off) ? s[t - off] : 0;
        __syncthreads();
        s[t] += x;
        __syncthreads();
    }
    if (i < n) row_ptr[i + 1] = s[t];
    if (t == 255) blockSums[blockIdx.x] = s[255];
}

__global__ __launch_bounds__(256) void k_scan2(const int* __restrict__ blockSums, int* __restrict__ blockOff, int nb) {
    __shared__ int s[256];
    int t = threadIdx.x;
    s[t] = (t < nb) ? blockSums[t] : 0;
    __syncthreads();
    for (int off = 1; off < 256; off <<= 1) {
        int x = (t >= off) ? s[t - off] : 0;
        __syncthreads();
        s[t] += x;
        __syncthreads();
    }
    blockOff[t] = (t == 0) ? 0 : s[t - 1];
}

__global__ __launch_bounds__(256) void k_scan3(int* __restrict__ row_ptr, const int* __restrict__ blockOff, int n) {
    int i = blockIdx.x * 256 + threadIdx.x;
    if (i < n) row_ptr[i + 1] += blockOff[blockIdx.x];
    if (blockIdx.x == 0 && threadIdx.x == 0) row_ptr[0] = 0;
}

// int2-packed scatter: one 8B store per edge (halves dirtied cache lines vs 2x4B)
__global__ __launch_bounds__(256) void k_scatter(const int* __restrict__ src, const int* __restrict__ dst,
                                                 const int* __restrict__ row_ptr, int* __restrict__ cursor,
                                                 int2* __restrict__ sed, int E) {
    int e = blockIdx.x * 256 + threadIdx.x;
    if (e < E) {
        int d = dst[e];
        int pos = row_ptr[d] + atomicAdd(&cursor[d], 1);
        sed[pos] = make_int2(src[e], d);
    }
}

// ---------------- node GEMM: [P|Q] = act @ WcT^T, P gets +b1. 256 rows/block ----------------
__global__ __launch_bounds__(256) void k_gemm1(const f16* __restrict__ act, const f16* __restrict__ WcT,
                                               const float* __restrict__ b1,
                                               f16* __restrict__ P, f16* __restrict__ Q, int nrows) {
    int t = threadIdx.x;
    int w = t >> 6, lane = t & 63;
    int m = lane & 15, q = lane >> 4;
    int rowbase = blockIdx.x * 256 + w * 64;
    f16x8 a[4][4];   // [row-tile][kk]
#pragma unroll
    for (int rt = 0; rt < 4; ++rt) {
        int rowc = min(rowbase + rt * 16 + m, nrows - 1);
#pragma unroll
        for (int kk = 0; kk < 4; ++kk)
            a[rt][kk] = *(const f16x8*)(act + (size_t)rowc * CH + kk * 32 + q * 8);
    }
#pragma unroll
    for (int nb = 0; nb < 16; ++nb) {
        f16x8 b[4];
#pragma unroll
        for (int kk = 0; kk < 4; ++kk)
            b[kk] = *(const f16x8*)(WcT + (nb * 16 + m) * CH + kk * 32 + q * 8);
        int col = nb * 16 + m;
        float bias = (nb < 8) ? b1[col] : 0.f;
#pragma unroll
        for (int rt = 0; rt < 4; ++rt) {
            f32x4 acc = {0.f, 0.f, 0.f, 0.f};
#pragma unroll
            for (int kk = 0; kk < 4; ++kk) acc = mfma16(a[rt][kk], b[kk], acc);
#pragma unroll
            for (int r = 0; r < 4; ++r) {
                int ro = rowbase + rt * 16 + q * 4 + r;
                if (ro < nrows) {
                    float v = acc[r] + bias;
                    if (nb < 8) P[(size_t)ro * CH + col] = (f16)v;
                    else        Q[(size_t)ro * CH + (col - CH)] = (f16)v;
                }
            }
        }
    }
}

// ---------------- fused edge GEMM + segmented max: PACKED 32-edge tiles ----------------
// Per-step barrier is lgkmcnt-only (bar_lds) so global prefetches for tiles i+2/i+3
// remain in flight across it; compiler inserts precise vmcnt(N) waits at first use.
// flags: bit0 relu out, bit1 fp32 final out.
__global__ __launch_bounds__(256) void k_edge(const f16* __restrict__ P, const f16* __restrict__ Q,
                                              const f16* __restrict__ W2Tg, const float* __restrict__ b2,
                                              const int* __restrict__ row_ptr, const int2* __restrict__ sed,
                                              f16* __restrict__ act_out, float* __restrict__ final_out,
                                              int n_nodes, int flags) {
    __shared__ __align__(16) f16 buf[2][32 * 136];
    __shared__ unsigned char ndrel[2][32];
    __shared__ unsigned accs[NPB * CH];

    int t = threadIdx.x;
    int w = t >> 6, lane = t & 63;
    int m1 = lane & 15, q1 = lane >> 4;   // consumer coords
    int mp = t >> 4, c = t & 15;          // producer coords: slot, chunk
    int n0 = blockIdx.x * NPB;
    const f16x8 z8 = {};

#pragma unroll
    for (int i = t; i < NPB * CH; i += 256) accs[i] = 0u;

    int rs = row_ptr[min(n0, n_nodes)];
    int re = row_ptr[min(n0 + NPB, n_nodes)];
    int ntiles = (re - rs + 31) >> 5;

    // this wave's 2 nb-blocks of W2^T (32 VGPRs)
    f16x8 bf[2][4];
#pragma unroll
    for (int i2 = 0; i2 < 2; ++i2)
#pragma unroll
        for (int kk = 0; kk < 4; ++kk)
            bf[i2][kk] = *(const f16x8*)(W2Tg + ((2 * w + i2) * 16 + m1) * CH + kk * 32 + q1 * 8);

    auto flip = [](float x) -> unsigned {
        unsigned u = __float_as_uint(x);
        return u ^ (0x80000000u | (unsigned)((int)u >> 31));
    };

    auto consume = [&](int par) {
#pragma unroll
        for (int rt = 0; rt < 2; ++rt) {
            f16x8 af[4];
#pragma unroll
            for (int kk = 0; kk < 4; ++kk)
                af[kk] = *(const f16x8*)&buf[par][(rt * 16 + m1) * 136 + kk * 32 + q1 * 8];
            unsigned nid4 = *(const unsigned*)&ndrel[par][rt * 16 + q1 * 4];
            unsigned b0 = nid4 & 255u;
            bool uni = (nid4 == b0 * 0x01010101u);
#pragma unroll
            for (int i2 = 0; i2 < 2; ++i2) {
                f32x4 a = {0.f, 0.f, 0.f, 0.f};
#pragma unroll
                for (int kk = 0; kk < 4; ++kk) a = mfma16(af[kk], bf[i2][kk], a);
                int col = (2 * w + i2) * 16 + m1;
                if (uni) {
                    float m = fmaxf(fmaxf(a[0], a[1]), fmaxf(a[2], a[3]));
                    atomicMax(&accs[b0 * CH + col], flip(m));
                } else {
#pragma unroll
                    for (int r = 0; r < 4; ++r) {
                        int node = (nid4 >> (8 * r)) & 255;
                        atomicMax(&accs[node * CH + col], flip(a[r]));
                    }
                }
            }
        }
    };

    if (ntiles > 0) {
        // pipeline regs: idx sets (x=src, y=dst) and data sets, 2 parities
        int2 ia0, ib0, ia1, ib1;
        f16x8 qa0, pa0, qb0, pb0, qa1, pa1, qb1, pb1;

        auto loadIdx = [&](int tt, int2& ia, int2& ib) {
            int e0 = rs + tt * 32;
            ia = sed[min(e0 + mp, re - 1)];
            ib = sed[min(e0 + 16 + mp, re - 1)];
        };
        auto loadData = [&](int2 ia, int2 ib,
                            f16x8& qa, f16x8& pa, f16x8& qb, f16x8& pb) {
            qa = *(const f16x8*)(Q + (size_t)ia.x * CH + c * 8);
            pa = *(const f16x8*)(P + (size_t)ia.y * CH + c * 8);
            qb = *(const f16x8*)(Q + (size_t)ib.x * CH + c * 8);
            pb = *(const f16x8*)(P + (size_t)ib.y * CH + c * 8);
        };
        auto produce = [&](int par, f16x8 qa, f16x8 pa, f16x8 qb, f16x8 pb, int da, int db) {
            *(f16x8*)&buf[par][mp * 136 + c * 8]        = __builtin_elementwise_max(pa + qa, z8);
            *(f16x8*)&buf[par][(16 + mp) * 136 + c * 8] = __builtin_elementwise_max(pb + qb, z8);
            if (c == 0) {
                ndrel[par][mp]      = (unsigned char)(da - n0);
                ndrel[par][16 + mp] = (unsigned char)(db - n0);
            }
        };

        // prologue: tile0 -> buf0; data(1) -> set1; idx(2) -> set0
        loadIdx(0, ia0, ib0);
        loadData(ia0, ib0, qa0, pa0, qb0, pb0);
        produce(0, qa0, pa0, qb0, pb0, ia0.y, ib0.y);
        if (ntiles > 1) {
            loadIdx(1, ia1, ib1);
            loadData(ia1, ib1, qa1, pa1, qb1, pb1);
        }
        if (ntiles > 2) loadIdx(2, ia0, ib0);
        bar_lds();

        auto step = [&](int i, int par,
                        f16x8& pqa, f16x8& ppa, f16x8& pqb, f16x8& ppb, int pda, int pdb, // data+dst for tile i+1
                        f16x8& nqa, f16x8& npa, f16x8& nqb, f16x8& npb,                   // fill: data tile i+2
                        int2 i2a, int2 i2b,                                               // idx for tile i+2
                        int2& i3a, int2& i3b) {                                            // fill: idx tile i+3
            if (i + 3 < ntiles) loadIdx(i + 3, i3a, i3b);
            if (i + 2 < ntiles) loadData(i2a, i2b, nqa, npa, nqb, npb);
            consume(par);
            if (i + 1 < ntiles) produce(par ^ 1, pqa, ppa, pqb, ppb, pda, pdb);
            bar_lds();   // LDS-only barrier: global prefetches stay in flight
        };

        int i = 0;
        while (i < ntiles) {
            step(i, 0, qa1, pa1, qb1, pb1, ia1.y, ib1.y, qa0, pa0, qb0, pb0,
                 ia0, ib0, ia1, ib1); ++i;
            if (i >= ntiles) break;
            step(i, 1, qa0, pa0, qb0, pb0, ia0.y, ib0.y, qa1, pa1, qb1, pb1,
                 ia1, ib1, ia0, ib0); ++i;
        }
    }
    bar_lds();

    // writeback: unflip + bias (+relu), zero-degree -> 0
#pragma unroll
    for (int j = 0; j < NPB * CH / 256; ++j) {
        int idx = t + j * 256;
        int node = idx >> 7, col = idx & 127;
        int gn = n0 + node;
        if (gn < n_nodes) {
            unsigned u = accs[idx];
            float o = 0.f;
            if (u != 0u) {
                float v = (u & 0x80000000u) ? __uint_as_float(u & 0x7FFFFFFFu)
                                            : __uint_as_float(~u);
                o = v + b2[col];
                if (flags & 1) o = fmaxf(o, 0.f);
            }
            if (flags & 2) final_out[(size_t)gn * CH + col] = o;
            else           act_out[(size_t)gn * CH + col] = (f16)o;
        }
    }
}

extern "C" void kernel_launch(void* const* d_in, const int* in_sizes, int n_in,
                              void* d_out, int out_size, void* d_ws, size_t ws_size,
                              hipStream_t stream) {
    const float* x = (const float*)d_in[0];
    const int* ei  = (const int*)d_in[1];
    int E = in_sizes[1] / 2;
    int N = in_sizes[0] / CH;
    const int* esrc = ei;
    const int* edst = ei + E;

    const float* W1[3] = {(const float*)d_in[2], (const float*)d_in[6],  (const float*)d_in[10]};
    const float* B1[3] = {(const float*)d_in[3], (const float*)d_in[7],  (const float*)d_in[11]};
    const float* W2[3] = {(const float*)d_in[4], (const float*)d_in[8],  (const float*)d_in[12]};
    const float* B2[3] = {(const float*)d_in[5], (const float*)d_in[9],  (const float*)d_in[13]};

    char* base = (char*)d_ws;
    size_t off = 0;
    auto alloc = [&](size_t bytes) -> void* {
        void* p = base + off;
        off = (off + bytes + 255) & ~(size_t)255;
        return p;
    };
    int* counts    = (int*)alloc(sizeof(int) * (size_t)(N + 256));
    int* cursor    = (int*)alloc(sizeof(int) * (size_t)(N + 256));
    size_t zero_bytes = off;                       // counts + cursor must start at 0
    int* row_ptr   = (int*)alloc(sizeof(int) * (size_t)(N + 1));
    int* blockSums = (int*)alloc(sizeof(int) * 256);
    int* blockOff  = (int*)alloc(sizeof(int) * 256);
    int2* sed      = (int2*)alloc(sizeof(int2) * (size_t)E);
    f16* act       = (f16*)alloc(sizeof(f16) * (size_t)N * CH);
    f16* Pb        = (f16*)alloc(sizeof(f16) * (size_t)N * CH);
    f16* Qb        = (f16*)alloc(sizeof(f16) * (size_t)N * CH);
    f16* WcT       = (f16*)alloc(sizeof(f16) * 3 * 256 * CH);
    f16* W2T       = (f16*)alloc(sizeof(f16) * 3 * CH * CH);

    hipMemsetAsync(d_ws, 0, zero_bytes, stream);

    int gE = (E + 255) / 256;
    int gN = (N + 255) / 256;
    int total4 = N * CH / 4;
    int gCvt = (total4 + 255) / 256;
    // fused: hist + 3x prep + cvt
    k_front<<<gE + 576 + gCvt, 256, 0, stream>>>(edst, counts, E,
                                                 W1[0], W2[0], W1[1], W2[1], W1[2], W2[2],
                                                 WcT, W2T, x, act, total4, gE);
    k_scan1<<<gN, 256, 0, stream>>>(counts, row_ptr, blockSums, N);
    k_scan2<<<1, 256, 0, stream>>>(blockSums, blockOff, gN);
    k_scan3<<<gN, 256, 0, stream>>>(row_ptr, blockOff, N);
    k_scatter<<<gE, 256, 0, stream>>>(esrc, edst, row_ptr, cursor, sed, E);

    int gEdge = (N + NPB - 1) / NPB;
    int gG1 = (N + 255) / 256;
    for (int l = 0; l < 3; ++l) {
        k_gemm1<<<gG1, 256, 0, stream>>>(act, WcT + l * 256 * CH, B1[l], Pb, Qb, N);
        int flags = (l < 2) ? 1 : 2;
        k_edge<<<gEdge, 256, 0, stream>>>(Pb, Qb, W2T + l * CH * CH, B2[l],
                                          row_ptr, sed, act, (float*)d_out, N, flags);
    }
}